// Round 19
// baseline (786.348 us; speedup 1.0000x reference)
//
#include <hip/hip_runtime.h>

#define NB 16
#define NL 1024
#define ND 64
#define NW 20
#define CH 16                   // l's per block (rolling)
#define THR 0.3f
#define REP_ST 8

typedef float f32x4 __attribute__((ext_vector_type(4)));

// ========== R19: decisive store-BW probes (rep-rotated chunks so L2 can't
// ========== merge reps; 2.1 GB each -> top-5 rows with WRITE_SIZE/hbm_gbps).
// Models in contention for real kernel's 56.3us (floor ~39):
//   A: zero compute/store overlap (39 + 17 additive)
//   B: the store PATTERN itself caps at ~4.8 TB/s
// pattern probe = real kernel's exact address stream; linear = fill-style.

// --- (1) pattern probe: real-kernel store addresses ---
__global__ void store_pattern_kernel(const float* __restrict__ x,
                                     float* __restrict__ out)
{
    const int t  = threadIdx.x;
    const int q  = t >> 6;
    const int g  = (t >> 4) & 3;
    const int tc = t & 15;
    const int r0 = (q << 4) + g;
    const int e0 = tc << 2;

    f32x4 v = *(const f32x4*)&x[(size_t)(t * 4)];

    for (int r = 0; r < REP_ST; ++r) {
        int blk = (blockIdx.x + r * 131) & 1023;   // bijective rotation
        int b   = blk >> 6;
        int l0  = (blk & 63) * CH;
        float* obase = out + ((size_t)b * NL + l0) * (ND * ND);
        v.x += 1.0f;                                // defeat CSE
        for (int s = 0; s < CH; ++s) {
            float* ob = obase + (size_t)s * (ND * ND);
            #pragma unroll
            for (int i = 0; i < 4; ++i)
                __builtin_nontemporal_store(v, (f32x4*)&ob[(r0 + 4 * i) * ND + e0]);
        }
    }
}

// --- (2) linear probe: same grid, fill-style contiguous march ---
__global__ void store_linear_kernel(const float* __restrict__ x,
                                    float* __restrict__ out)
{
    const int t = threadIdx.x;
    f32x4 v = *(const f32x4*)&x[(size_t)(t * 4)];

    for (int r = 0; r < REP_ST; ++r) {
        int blk = (blockIdx.x + r * 131) & 1023;
        float* obase = out + (size_t)blk * 65536;   // 256 KB chunk
        v.x += 1.0f;
        for (int s = 0; s < 64; ++s)                // 64 x 256thr x 16B = 256KB
            __builtin_nontemporal_store(v, (f32x4*)&obase[(size_t)(s * 256 + t) * 4]);
    }
}

// --- (3) real kernel: R15 + unroll 4 ---
__global__ void dyn_corr_kernel(
    const float* __restrict__ x, float* __restrict__ out)
{
    const int blk = blockIdx.x;            // 0..1023
    const int b   = blk >> 6;
    const int l0  = (blk & 63) * CH;
    const int t   = threadIdx.x;           // 0..255

    const int NROW = NW - 1 + CH;          // 35 staged rows
    __shared__ float win[NW - 1 + CH][ND]; // 8960 B, raw (uncentered)

    const float* xb = x + ((size_t)b * NL) * ND;

    #pragma unroll
    for (int i = 0; i < 3; ++i) {
        int s = t + i * 256;               // valid < 560
        if (s < NROW * 16) {
            int w    = s >> 4;
            int c4   = (s & 15) << 2;
            int lsrc = l0 - (NW - 1) + w;
            f32x4 v = {0.f, 0.f, 0.f, 0.f};
            if (lsrc >= 0) v = *(const f32x4*)&xb[(size_t)lsrc * ND + c4];
            *(f32x4*)&win[w][c4] = v;
        }
    }
    __syncthreads();                       // win read-only from here on

    const int q  = t >> 6;                 // wave 0..3 -> rows 16q..16q+15
    const int g  = (t >> 4) & 3;           // row-group within wave
    const int tc = t & 15;                 // col group
    const int r0 = (q << 4) + g;           // row(i) = r0 + 4*i
    const int e0 = tc << 2;                // cols e0..e0+3

    float acc[4][4] = {};                  // raw Gram tile (row i, col j)
    float rs[4] = {}, rq[4] = {};          // row sum / sumsq
    float cs[4] = {}, cq[4] = {};          // col sum / sumsq

    #pragma unroll
    for (int w = 0; w < NW; ++w) {
        float ar[4];
        ar[0] = win[w][r0];
        ar[1] = win[w][r0 + 4];
        ar[2] = win[w][r0 + 8];
        ar[3] = win[w][r0 + 12];
        f32x4 b0 = *(const f32x4*)&win[w][e0];
        float br[4] = {b0.x, b0.y, b0.z, b0.w};
        #pragma unroll
        for (int i = 0; i < 4; ++i) {
            rs[i] += ar[i];
            rq[i]  = fmaf(ar[i], ar[i], rq[i]);
            #pragma unroll
            for (int j = 0; j < 4; ++j)
                acc[i][j] = fmaf(ar[i], br[j], acc[i][j]);
        }
        #pragma unroll
        for (int j = 0; j < 4; ++j) {
            cs[j] += br[j];
            cq[j]  = fmaf(br[j], br[j], cq[j]);
        }
    }

    const float invW  = 1.0f / NW;
    const float EPS19 = 19e-8f;            // 19 * 1e-8 (rescaled ref eps)
    float* obase = out + ((size_t)b * NL + l0) * (ND * ND);

    #pragma unroll 4
    for (int s = 0; s < CH; ++s) {
        float sdu[4], seu[4], mc[4];
        #pragma unroll
        for (int i = 0; i < 4; ++i) {
            float qv = fmaf(-rs[i] * invW, rs[i], rq[i]);
            sdu[i] = __builtin_amdgcn_sqrtf(qv);
        }
        #pragma unroll
        for (int j = 0; j < 4; ++j) {
            mc[j] = cs[j] * invW;
            float qv = fmaf(-cs[j], mc[j], cq[j]);
            seu[j] = __builtin_amdgcn_sqrtf(qv);
        }
        float* ob = obase + (size_t)s * (ND * ND);
        #pragma unroll
        for (int i = 0; i < 4; ++i) {
            f32x4 o;
            float cv, rr;
            cv = fmaf(-rs[i], mc[0], acc[i][0]);
            rr = __builtin_amdgcn_rcpf(fmaf(sdu[i], seu[0], EPS19));
            o.x = fmaxf(fmaf(fabsf(cv), rr, -THR), 0.0f);
            cv = fmaf(-rs[i], mc[1], acc[i][1]);
            rr = __builtin_amdgcn_rcpf(fmaf(sdu[i], seu[1], EPS19));
            o.y = fmaxf(fmaf(fabsf(cv), rr, -THR), 0.0f);
            cv = fmaf(-rs[i], mc[2], acc[i][2]);
            rr = __builtin_amdgcn_rcpf(fmaf(sdu[i], seu[2], EPS19));
            o.z = fmaxf(fmaf(fabsf(cv), rr, -THR), 0.0f);
            cv = fmaf(-rs[i], mc[3], acc[i][3]);
            rr = __builtin_amdgcn_rcpf(fmaf(sdu[i], seu[3], EPS19));
            o.w = fmaxf(fmaf(fabsf(cv), rr, -THR), 0.0f);
            __builtin_nontemporal_store(o, (f32x4*)&ob[(r0 + 4 * i) * ND + e0]);
        }
        if (s < CH - 1) {
            float an[4], ao[4];
            an[0] = win[s + NW][r0];
            an[1] = win[s + NW][r0 + 4];
            an[2] = win[s + NW][r0 + 8];
            an[3] = win[s + NW][r0 + 12];
            ao[0] = win[s][r0];
            ao[1] = win[s][r0 + 4];
            ao[2] = win[s][r0 + 8];
            ao[3] = win[s][r0 + 12];
            f32x4 nb  = *(const f32x4*)&win[s + NW][e0];
            f32x4 obv = *(const f32x4*)&win[s][e0];
            float bn[4] = {nb.x, nb.y, nb.z, nb.w};
            float bo[4] = {obv.x, obv.y, obv.z, obv.w};
            #pragma unroll
            for (int i = 0; i < 4; ++i) {
                rs[i] += an[i] - ao[i];
                rq[i]  = fmaf(an[i], an[i], fmaf(-ao[i], ao[i], rq[i]));
                #pragma unroll
                for (int j = 0; j < 4; ++j)
                    acc[i][j] = fmaf(an[i], bn[j], fmaf(-ao[i], bo[j], acc[i][j]));
            }
            #pragma unroll
            for (int j = 0; j < 4; ++j) {
                cs[j] += bn[j] - bo[j];
                cq[j]  = fmaf(bn[j], bn[j], fmaf(-bo[j], bo[j], cq[j]));
            }
        }
    }
}

extern "C" void kernel_launch(void* const* d_in, const int* in_sizes, int n_in,
                              void* d_out, int out_size, void* d_ws, size_t ws_size,
                              hipStream_t stream) {
    const float* x = (const float*)d_in[0];
    float* out = (float*)d_out;
    dim3 grid(NB * (NL / CH));
    dim3 block(256);
    // probes scribble d_out; real kernel rewrites every element correctly
    hipLaunchKernelGGL(store_pattern_kernel, grid, block, 0, stream, x, out);
    hipLaunchKernelGGL(store_linear_kernel, grid, block, 0, stream, x, out);
    hipLaunchKernelGGL(dyn_corr_kernel, grid, block, 0, stream, x, out);
}

// Round 20
// 56.709 us; speedup vs baseline: 13.8664x; 13.8664x over previous
//
#include <hip/hip_runtime.h>

#define NB 16
#define NL 1024
#define ND 64
#define NW 20
#define CH 8                    // l's per block (rolling) — 2048 blocks
#define THR 0.3f

typedef float f32x4 __attribute__((ext_vector_type(4)));

// Rolling-window, 256 threads per (b, 8-l chunk), strided row ownership
// (1KB contiguous per store instr), slim epilogue (raw v_sqrt/v_rcp).
// R20: CH=8 -> 8 blocks/CU (vs CH=16's exact-fit 4): block retirement
// creates a pipeline where later blocks' staging/init overlaps earlier
// blocks' store drain. R19 proved the store pattern sustains >=6.3 TB/s
// bare (Model B dead); real kernel's 56.3us = 41us drain + ~15us EXPOSED
// compute (Model A). This attacks the exposure.
// EPILOGUE eps EXACT (x19-rescale): den = sdu*seu + 19e-8 == 19*(sd*se+1e-8).
// RULES: no runtime indexing into register arrays (R5); no __launch_bounds__
// (R3/R4); keep eps INSIDE the divide (R8).
__global__ void dyn_corr_kernel(
    const float* __restrict__ x, float* __restrict__ out)
{
    const int blk = blockIdx.x;            // 0..2047
    const int b   = blk >> 7;              // 128 chunks per batch
    const int l0  = (blk & 127) * CH;
    const int t   = threadIdx.x;           // 0..255

    const int NROW = NW - 1 + CH;          // 27 staged rows: l0-19 .. l0+7
    __shared__ float win[NW - 1 + CH][ND]; // 6912 B

    const float* xb = x + ((size_t)b * NL) * ND;

    // --- stage 27 rows (zeros for l<0), f32x4, coalesced ---
    #pragma unroll
    for (int i = 0; i < 2; ++i) {
        int s = t + i * 256;               // valid < 432
        if (s < NROW * 16) {
            int w    = s >> 4;
            int c4   = (s & 15) << 2;
            int lsrc = l0 - (NW - 1) + w;
            f32x4 v = {0.f, 0.f, 0.f, 0.f};
            if (lsrc >= 0) v = *(const f32x4*)&xb[(size_t)lsrc * ND + c4];
            *(f32x4*)&win[w][c4] = v;
        }
    }
    __syncthreads();                       // win read-only from here on

    const int q  = t >> 6;                 // wave 0..3 -> rows 16q..16q+15
    const int g  = (t >> 4) & 3;           // row-group within wave
    const int tc = t & 15;                 // col group
    const int r0 = (q << 4) + g;           // row(i) = r0 + 4*i
    const int e0 = tc << 2;                // cols e0..e0+3

    float acc[4][4] = {};                  // raw Gram tile (row i, col j)
    float rs[4] = {}, rq[4] = {};          // row sum / sumsq
    float cs[4] = {}, cq[4] = {};          // col sum / sumsq

    #pragma unroll
    for (int w = 0; w < NW; ++w) {
        float ar[4];
        ar[0] = win[w][r0];
        ar[1] = win[w][r0 + 4];
        ar[2] = win[w][r0 + 8];
        ar[3] = win[w][r0 + 12];
        f32x4 b0 = *(const f32x4*)&win[w][e0];
        float br[4] = {b0.x, b0.y, b0.z, b0.w};
        #pragma unroll
        for (int i = 0; i < 4; ++i) {
            rs[i] += ar[i];
            rq[i]  = fmaf(ar[i], ar[i], rq[i]);
            #pragma unroll
            for (int j = 0; j < 4; ++j)
                acc[i][j] = fmaf(ar[i], br[j], acc[i][j]);
        }
        #pragma unroll
        for (int j = 0; j < 4; ++j) {
            cs[j] += br[j];
            cq[j]  = fmaf(br[j], br[j], cq[j]);
        }
    }

    const float invW  = 1.0f / NW;
    const float EPS19 = 19e-8f;            // 19 * 1e-8 (rescaled ref eps)
    float* obase = out + ((size_t)b * NL + l0) * (ND * ND);

    #pragma unroll 4
    for (int s = 0; s < CH; ++s) {
        float sdu[4], seu[4], mc[4];
        #pragma unroll
        for (int i = 0; i < 4; ++i) {
            float qv = fmaf(-rs[i] * invW, rs[i], rq[i]);
            sdu[i] = __builtin_amdgcn_sqrtf(qv);
        }
        #pragma unroll
        for (int j = 0; j < 4; ++j) {
            mc[j] = cs[j] * invW;
            float qv = fmaf(-cs[j], mc[j], cq[j]);
            seu[j] = __builtin_amdgcn_sqrtf(qv);
        }
        float* ob = obase + (size_t)s * (ND * ND);
        #pragma unroll
        for (int i = 0; i < 4; ++i) {
            f32x4 o;
            float cv, rr;
            cv = fmaf(-rs[i], mc[0], acc[i][0]);
            rr = __builtin_amdgcn_rcpf(fmaf(sdu[i], seu[0], EPS19));
            o.x = fmaxf(fmaf(fabsf(cv), rr, -THR), 0.0f);
            cv = fmaf(-rs[i], mc[1], acc[i][1]);
            rr = __builtin_amdgcn_rcpf(fmaf(sdu[i], seu[1], EPS19));
            o.y = fmaxf(fmaf(fabsf(cv), rr, -THR), 0.0f);
            cv = fmaf(-rs[i], mc[2], acc[i][2]);
            rr = __builtin_amdgcn_rcpf(fmaf(sdu[i], seu[2], EPS19));
            o.z = fmaxf(fmaf(fabsf(cv), rr, -THR), 0.0f);
            cv = fmaf(-rs[i], mc[3], acc[i][3]);
            rr = __builtin_amdgcn_rcpf(fmaf(sdu[i], seu[3], EPS19));
            o.w = fmaxf(fmaf(fabsf(cv), rr, -THR), 0.0f);
            __builtin_nontemporal_store(o, (f32x4*)&ob[(r0 + 4 * i) * ND + e0]);
        }
        if (s < CH - 1) {
            float an[4], ao[4];
            an[0] = win[s + NW][r0];
            an[1] = win[s + NW][r0 + 4];
            an[2] = win[s + NW][r0 + 8];
            an[3] = win[s + NW][r0 + 12];
            ao[0] = win[s][r0];
            ao[1] = win[s][r0 + 4];
            ao[2] = win[s][r0 + 8];
            ao[3] = win[s][r0 + 12];
            f32x4 nb  = *(const f32x4*)&win[s + NW][e0];
            f32x4 obv = *(const f32x4*)&win[s][e0];
            float bn[4] = {nb.x, nb.y, nb.z, nb.w};
            float bo[4] = {obv.x, obv.y, obv.z, obv.w};
            #pragma unroll
            for (int i = 0; i < 4; ++i) {
                rs[i] += an[i] - ao[i];
                rq[i]  = fmaf(an[i], an[i], fmaf(-ao[i], ao[i], rq[i]));
                #pragma unroll
                for (int j = 0; j < 4; ++j)
                    acc[i][j] = fmaf(an[i], bn[j], fmaf(-ao[i], bo[j], acc[i][j]));
            }
            #pragma unroll
            for (int j = 0; j < 4; ++j) {
                cs[j] += bn[j] - bo[j];
                cq[j]  = fmaf(bn[j], bn[j], fmaf(-bo[j], bo[j], cq[j]));
            }
        }
    }
}

extern "C" void kernel_launch(void* const* d_in, const int* in_sizes, int n_in,
                              void* d_out, int out_size, void* d_ws, size_t ws_size,
                              hipStream_t stream) {
    const float* x = (const float*)d_in[0];
    float* out = (float*)d_out;
    dim3 grid(NB * (NL / CH));
    dim3 block(256);
    hipLaunchKernelGGL(dyn_corr_kernel, grid, block, 0, stream, x, out);
}

// Round 21
// 55.856 us; speedup vs baseline: 14.0782x; 1.0153x over previous
//
#include <hip/hip_runtime.h>

#define NB 16
#define NL 1024
#define ND 64
#define NW 20
#define CH 16                   // l's per block (rolling)
#define THR 0.3f

typedef float f32x4 __attribute__((ext_vector_type(4)));

// Rolling-window, 256 threads per (b, 16-l chunk), strided row ownership
// (1KB contiguous per store instr), slim epilogue (raw v_sqrt/v_rcp).
// R21: MANUAL PING-PONG STORE PIPELINE. R19 proved bare pattern >= 6.3 TB/s;
// R14/R17 proved slim compute ~19us; real = 41 + 15 additive. Diagnosis:
// compiler reuses store data+address VGPRs each iteration (VGPR_Count 84),
// forcing a ~vmcnt(0) drain per step; lockstep waves -> write pipe idles
// during every compute phase. unroll N doesn't help (allocator merges the
// N copies' registers). Fix: two NAMED register sets oA*/oB* whose live
// ranges overlap (oA computed -> oB computed+stored -> oA stored), so each
// set's stores are in flight during the other's compute.
// EPILOGUE eps EXACT: den = sdu*seu + 19e-8 == 19*(sd*se + 1e-8) (R8).
// RULES: no runtime indexing into register arrays (R5); no __launch_bounds__
// (R3/R4).
__global__ void dyn_corr_kernel(
    const float* __restrict__ x, float* __restrict__ out)
{
    const int blk = blockIdx.x;            // 0..1023
    const int b   = blk >> 6;              // 64 chunks per batch
    const int l0  = (blk & 63) * CH;
    const int t   = threadIdx.x;           // 0..255

    const int NROW = NW - 1 + CH;          // 35 staged rows
    __shared__ float win[NW - 1 + CH][ND]; // 8960 B

    const float* xb = x + ((size_t)b * NL) * ND;

    #pragma unroll
    for (int i = 0; i < 3; ++i) {
        int s = t + i * 256;               // valid < 560
        if (s < NROW * 16) {
            int w    = s >> 4;
            int c4   = (s & 15) << 2;
            int lsrc = l0 - (NW - 1) + w;
            f32x4 v = {0.f, 0.f, 0.f, 0.f};
            if (lsrc >= 0) v = *(const f32x4*)&xb[(size_t)lsrc * ND + c4];
            *(f32x4*)&win[w][c4] = v;
        }
    }
    __syncthreads();                       // win read-only from here on

    const int q  = t >> 6;                 // wave 0..3 -> rows 16q..16q+15
    const int g  = (t >> 4) & 3;           // row-group within wave
    const int tc = t & 15;                 // col group
    const int r0 = (q << 4) + g;           // row(i) = r0 + 4*i
    const int e0 = tc << 2;                // cols e0..e0+3

    float acc[4][4] = {};
    float rs[4] = {}, rq[4] = {};
    float cs[4] = {}, cq[4] = {};

    #pragma unroll
    for (int w = 0; w < NW; ++w) {
        float ar[4];
        ar[0] = win[w][r0];
        ar[1] = win[w][r0 + 4];
        ar[2] = win[w][r0 + 8];
        ar[3] = win[w][r0 + 12];
        f32x4 b0 = *(const f32x4*)&win[w][e0];
        float br[4] = {b0.x, b0.y, b0.z, b0.w};
        #pragma unroll
        for (int i = 0; i < 4; ++i) {
            rs[i] += ar[i];
            rq[i]  = fmaf(ar[i], ar[i], rq[i]);
            #pragma unroll
            for (int j = 0; j < 4; ++j)
                acc[i][j] = fmaf(ar[i], br[j], acc[i][j]);
        }
        #pragma unroll
        for (int j = 0; j < 4; ++j) {
            cs[j] += br[j];
            cq[j]  = fmaf(br[j], br[j], cq[j]);
        }
    }

    const float invW  = 1.0f / NW;
    const float EPS19 = 19e-8f;
    float* obase = out + ((size_t)b * NL + l0) * (ND * ND);

    // EPI(s, o0..o3): compute the 4 output vectors for step s.
    #define EPI(S, O0, O1, O2, O3)                                         \
    {                                                                      \
        float sdu[4], seu[4], mc[4];                                       \
        _Pragma("unroll")                                                  \
        for (int i = 0; i < 4; ++i) {                                      \
            float qv = fmaf(-rs[i] * invW, rs[i], rq[i]);                  \
            sdu[i] = __builtin_amdgcn_sqrtf(qv);                           \
        }                                                                  \
        _Pragma("unroll")                                                  \
        for (int j = 0; j < 4; ++j) {                                      \
            mc[j] = cs[j] * invW;                                          \
            float qv = fmaf(-cs[j], mc[j], cq[j]);                         \
            seu[j] = __builtin_amdgcn_sqrtf(qv);                           \
        }                                                                  \
        float cv, rr;                                                      \
        cv = fmaf(-rs[0], mc[0], acc[0][0]);                               \
        rr = __builtin_amdgcn_rcpf(fmaf(sdu[0], seu[0], EPS19));           \
        O0.x = fmaxf(fmaf(fabsf(cv), rr, -THR), 0.0f);                     \
        cv = fmaf(-rs[0], mc[1], acc[0][1]);                               \
        rr = __builtin_amdgcn_rcpf(fmaf(sdu[0], seu[1], EPS19));           \
        O0.y = fmaxf(fmaf(fabsf(cv), rr, -THR), 0.0f);                     \
        cv = fmaf(-rs[0], mc[2], acc[0][2]);                               \
        rr = __builtin_amdgcn_rcpf(fmaf(sdu[0], seu[2], EPS19));           \
        O0.z = fmaxf(fmaf(fabsf(cv), rr, -THR), 0.0f);                     \
        cv = fmaf(-rs[0], mc[3], acc[0][3]);                               \
        rr = __builtin_amdgcn_rcpf(fmaf(sdu[0], seu[3], EPS19));           \
        O0.w = fmaxf(fmaf(fabsf(cv), rr, -THR), 0.0f);                     \
        cv = fmaf(-rs[1], mc[0], acc[1][0]);                               \
        rr = __builtin_amdgcn_rcpf(fmaf(sdu[1], seu[0], EPS19));           \
        O1.x = fmaxf(fmaf(fabsf(cv), rr, -THR), 0.0f);                     \
        cv = fmaf(-rs[1], mc[1], acc[1][1]);                               \
        rr = __builtin_amdgcn_rcpf(fmaf(sdu[1], seu[1], EPS19));           \
        O1.y = fmaxf(fmaf(fabsf(cv), rr, -THR), 0.0f);                     \
        cv = fmaf(-rs[1], mc[2], acc[1][2]);                               \
        rr = __builtin_amdgcn_rcpf(fmaf(sdu[1], seu[2], EPS19));           \
        O1.z = fmaxf(fmaf(fabsf(cv), rr, -THR), 0.0f);                     \
        cv = fmaf(-rs[1], mc[3], acc[1][3]);                               \
        rr = __builtin_amdgcn_rcpf(fmaf(sdu[1], seu[3], EPS19));           \
        O1.w = fmaxf(fmaf(fabsf(cv), rr, -THR), 0.0f);                     \
        cv = fmaf(-rs[2], mc[0], acc[2][0]);                               \
        rr = __builtin_amdgcn_rcpf(fmaf(sdu[2], seu[0], EPS19));           \
        O2.x = fmaxf(fmaf(fabsf(cv), rr, -THR), 0.0f);                     \
        cv = fmaf(-rs[2], mc[1], acc[2][1]);                               \
        rr = __builtin_amdgcn_rcpf(fmaf(sdu[2], seu[1], EPS19));           \
        O2.y = fmaxf(fmaf(fabsf(cv), rr, -THR), 0.0f);                     \
        cv = fmaf(-rs[2], mc[2], acc[2][2]);                               \
        rr = __builtin_amdgcn_rcpf(fmaf(sdu[2], seu[2], EPS19));           \
        O2.z = fmaxf(fmaf(fabsf(cv), rr, -THR), 0.0f);                     \
        cv = fmaf(-rs[2], mc[3], acc[2][3]);                               \
        rr = __builtin_amdgcn_rcpf(fmaf(sdu[2], seu[3], EPS19));           \
        O2.w = fmaxf(fmaf(fabsf(cv), rr, -THR), 0.0f);                     \
        cv = fmaf(-rs[3], mc[0], acc[3][0]);                               \
        rr = __builtin_amdgcn_rcpf(fmaf(sdu[3], seu[0], EPS19));           \
        O3.x = fmaxf(fmaf(fabsf(cv), rr, -THR), 0.0f);                     \
        cv = fmaf(-rs[3], mc[1], acc[3][1]);                               \
        rr = __builtin_amdgcn_rcpf(fmaf(sdu[3], seu[1], EPS19));           \
        O3.y = fmaxf(fmaf(fabsf(cv), rr, -THR), 0.0f);                     \
        cv = fmaf(-rs[3], mc[2], acc[3][2]);                               \
        rr = __builtin_amdgcn_rcpf(fmaf(sdu[3], seu[2], EPS19));           \
        O3.z = fmaxf(fmaf(fabsf(cv), rr, -THR), 0.0f);                     \
        cv = fmaf(-rs[3], mc[3], acc[3][3]);                               \
        rr = __builtin_amdgcn_rcpf(fmaf(sdu[3], seu[3], EPS19));           \
        O3.w = fmaxf(fmaf(fabsf(cv), rr, -THR), 0.0f);                     \
    }

    #define STORE4(S, O0, O1, O2, O3)                                      \
    {                                                                      \
        float* ob_ = obase + (size_t)(S) * (ND * ND);                      \
        __builtin_nontemporal_store(O0, (f32x4*)&ob_[(r0     ) * ND + e0]);\
        __builtin_nontemporal_store(O1, (f32x4*)&ob_[(r0 +  4) * ND + e0]);\
        __builtin_nontemporal_store(O2, (f32x4*)&ob_[(r0 +  8) * ND + e0]);\
        __builtin_nontemporal_store(O3, (f32x4*)&ob_[(r0 + 12) * ND + e0]);\
    }

    #define UPDATE(S)                                                      \
    {                                                                      \
        float an[4], ao[4];                                                \
        an[0] = win[(S) + NW][r0];                                         \
        an[1] = win[(S) + NW][r0 + 4];                                     \
        an[2] = win[(S) + NW][r0 + 8];                                     \
        an[3] = win[(S) + NW][r0 + 12];                                    \
        ao[0] = win[(S)][r0];                                              \
        ao[1] = win[(S)][r0 + 4];                                          \
        ao[2] = win[(S)][r0 + 8];                                          \
        ao[3] = win[(S)][r0 + 12];                                         \
        f32x4 nb  = *(const f32x4*)&win[(S) + NW][e0];                     \
        f32x4 obv = *(const f32x4*)&win[(S)][e0];                          \
        float bn[4] = {nb.x, nb.y, nb.z, nb.w};                            \
        float bo[4] = {obv.x, obv.y, obv.z, obv.w};                        \
        _Pragma("unroll")                                                  \
        for (int i = 0; i < 4; ++i) {                                      \
            rs[i] += an[i] - ao[i];                                        \
            rq[i]  = fmaf(an[i], an[i], fmaf(-ao[i], ao[i], rq[i]));       \
            _Pragma("unroll")                                              \
            for (int j = 0; j < 4; ++j)                                    \
                acc[i][j] = fmaf(an[i], bn[j], fmaf(-ao[i], bo[j], acc[i][j])); \
        }                                                                  \
        _Pragma("unroll")                                                  \
        for (int j = 0; j < 4; ++j) {                                      \
            cs[j] += bn[j] - bo[j];                                        \
            cq[j]  = fmaf(bn[j], bn[j], fmaf(-bo[j], bo[j], cq[j]));       \
        }                                                                  \
    }

    f32x4 oA0, oA1, oA2, oA3;
    f32x4 oB0, oB1, oB2, oB3;

    // prologue: step 0 into A, stores issued immediately
    EPI(0, oA0, oA1, oA2, oA3);
    UPDATE(0);
    STORE4(0, oA0, oA1, oA2, oA3);

    // steady state: compute one set while the other's stores are in flight
    #pragma unroll 1
    for (int k = 0; k < 7; ++k) {
        int s1 = 2 * k + 1;
        int s2 = 2 * k + 2;
        EPI(s1, oB0, oB1, oB2, oB3);       // oA stores in flight here
        UPDATE(s1);
        STORE4(s1, oB0, oB1, oB2, oB3);
        EPI(s2, oA0, oA1, oA2, oA3);       // oB stores in flight here
        UPDATE(s2);
        STORE4(s2, oA0, oA1, oA2, oA3);
    }

    // epilogue: step 15 (no update needed)
    EPI(15, oB0, oB1, oB2, oB3);
    STORE4(15, oB0, oB1, oB2, oB3);

    #undef EPI
    #undef STORE4
    #undef UPDATE
}

extern "C" void kernel_launch(void* const* d_in, const int* in_sizes, int n_in,
                              void* d_out, int out_size, void* d_ws, size_t ws_size,
                              hipStream_t stream) {
    const float* x = (const float*)d_in[0];
    float* out = (float*)d_out;
    dim3 grid(NB * (NL / CH));
    dim3 block(256);
    hipLaunchKernelGGL(dyn_corr_kernel, grid, block, 0, stream, x, out);
}

// Round 22
// 47.202 us; speedup vs baseline: 16.6593x; 1.1833x over previous
//
#include <hip/hip_runtime.h>

#define NB 16
#define NL 1024
#define ND 64
#define NW 20
#define CH 16                   // l's per block (rolling)
#define THR 0.3f

typedef float f32x4 __attribute__((ext_vector_type(4)));

// Rolling-window, 256 threads per (b, 16-l chunk), strided row ownership
// (1KB contiguous per store instr), slim epilogue (raw v_sqrt/v_rcp),
// ping-pong output register sets (R21).
// R22: PLAIN stores (drop nt). All slim-compute rounds used nt; nt bypasses
// L2 -> shallow buffering -> write pipe idles during compute phases ->
// additive 41+15. Normal stores buffer in the 32MB L2 and write back
// continuously, overlapping drain with compute at the memory level.
// (R11's nt-vs-plain null was under FAT compute — wrong regime, rule #23.)
// EPILOGUE eps EXACT: den = sdu*seu + 19e-8 == 19*(sd*se + 1e-8) (R8).
// RULES: no runtime indexing into register arrays (R5); no __launch_bounds__
// (R3/R4).
__global__ void dyn_corr_kernel(
    const float* __restrict__ x, float* __restrict__ out)
{
    const int blk = blockIdx.x;            // 0..1023
    const int b   = blk >> 6;              // 64 chunks per batch
    const int l0  = (blk & 63) * CH;
    const int t   = threadIdx.x;           // 0..255

    const int NROW = NW - 1 + CH;          // 35 staged rows
    __shared__ float win[NW - 1 + CH][ND]; // 8960 B

    const float* xb = x + ((size_t)b * NL) * ND;

    #pragma unroll
    for (int i = 0; i < 3; ++i) {
        int s = t + i * 256;               // valid < 560
        if (s < NROW * 16) {
            int w    = s >> 4;
            int c4   = (s & 15) << 2;
            int lsrc = l0 - (NW - 1) + w;
            f32x4 v = {0.f, 0.f, 0.f, 0.f};
            if (lsrc >= 0) v = *(const f32x4*)&xb[(size_t)lsrc * ND + c4];
            *(f32x4*)&win[w][c4] = v;
        }
    }
    __syncthreads();                       // win read-only from here on

    const int q  = t >> 6;                 // wave 0..3 -> rows 16q..16q+15
    const int g  = (t >> 4) & 3;           // row-group within wave
    const int tc = t & 15;                 // col group
    const int r0 = (q << 4) + g;           // row(i) = r0 + 4*i
    const int e0 = tc << 2;                // cols e0..e0+3

    float acc[4][4] = {};
    float rs[4] = {}, rq[4] = {};
    float cs[4] = {}, cq[4] = {};

    #pragma unroll
    for (int w = 0; w < NW; ++w) {
        float ar[4];
        ar[0] = win[w][r0];
        ar[1] = win[w][r0 + 4];
        ar[2] = win[w][r0 + 8];
        ar[3] = win[w][r0 + 12];
        f32x4 b0 = *(const f32x4*)&win[w][e0];
        float br[4] = {b0.x, b0.y, b0.z, b0.w};
        #pragma unroll
        for (int i = 0; i < 4; ++i) {
            rs[i] += ar[i];
            rq[i]  = fmaf(ar[i], ar[i], rq[i]);
            #pragma unroll
            for (int j = 0; j < 4; ++j)
                acc[i][j] = fmaf(ar[i], br[j], acc[i][j]);
        }
        #pragma unroll
        for (int j = 0; j < 4; ++j) {
            cs[j] += br[j];
            cq[j]  = fmaf(br[j], br[j], cq[j]);
        }
    }

    const float invW  = 1.0f / NW;
    const float EPS19 = 19e-8f;
    float* obase = out + ((size_t)b * NL + l0) * (ND * ND);

    #define EPI(S, O0, O1, O2, O3)                                         \
    {                                                                      \
        float sdu[4], seu[4], mc[4];                                       \
        _Pragma("unroll")                                                  \
        for (int i = 0; i < 4; ++i) {                                      \
            float qv = fmaf(-rs[i] * invW, rs[i], rq[i]);                  \
            sdu[i] = __builtin_amdgcn_sqrtf(qv);                           \
        }                                                                  \
        _Pragma("unroll")                                                  \
        for (int j = 0; j < 4; ++j) {                                      \
            mc[j] = cs[j] * invW;                                          \
            float qv = fmaf(-cs[j], mc[j], cq[j]);                         \
            seu[j] = __builtin_amdgcn_sqrtf(qv);                           \
        }                                                                  \
        float cv, rr;                                                      \
        cv = fmaf(-rs[0], mc[0], acc[0][0]);                               \
        rr = __builtin_amdgcn_rcpf(fmaf(sdu[0], seu[0], EPS19));           \
        O0.x = fmaxf(fmaf(fabsf(cv), rr, -THR), 0.0f);                     \
        cv = fmaf(-rs[0], mc[1], acc[0][1]);                               \
        rr = __builtin_amdgcn_rcpf(fmaf(sdu[0], seu[1], EPS19));           \
        O0.y = fmaxf(fmaf(fabsf(cv), rr, -THR), 0.0f);                     \
        cv = fmaf(-rs[0], mc[2], acc[0][2]);                               \
        rr = __builtin_amdgcn_rcpf(fmaf(sdu[0], seu[2], EPS19));           \
        O0.z = fmaxf(fmaf(fabsf(cv), rr, -THR), 0.0f);                     \
        cv = fmaf(-rs[0], mc[3], acc[0][3]);                               \
        rr = __builtin_amdgcn_rcpf(fmaf(sdu[0], seu[3], EPS19));           \
        O0.w = fmaxf(fmaf(fabsf(cv), rr, -THR), 0.0f);                     \
        cv = fmaf(-rs[1], mc[0], acc[1][0]);                               \
        rr = __builtin_amdgcn_rcpf(fmaf(sdu[1], seu[0], EPS19));           \
        O1.x = fmaxf(fmaf(fabsf(cv), rr, -THR), 0.0f);                     \
        cv = fmaf(-rs[1], mc[1], acc[1][1]);                               \
        rr = __builtin_amdgcn_rcpf(fmaf(sdu[1], seu[1], EPS19));           \
        O1.y = fmaxf(fmaf(fabsf(cv), rr, -THR), 0.0f);                     \
        cv = fmaf(-rs[1], mc[2], acc[1][2]);                               \
        rr = __builtin_amdgcn_rcpf(fmaf(sdu[1], seu[2], EPS19));           \
        O1.z = fmaxf(fmaf(fabsf(cv), rr, -THR), 0.0f);                     \
        cv = fmaf(-rs[1], mc[3], acc[1][3]);                               \
        rr = __builtin_amdgcn_rcpf(fmaf(sdu[1], seu[3], EPS19));           \
        O1.w = fmaxf(fmaf(fabsf(cv), rr, -THR), 0.0f);                     \
        cv = fmaf(-rs[2], mc[0], acc[2][0]);                               \
        rr = __builtin_amdgcn_rcpf(fmaf(sdu[2], seu[0], EPS19));           \
        O2.x = fmaxf(fmaf(fabsf(cv), rr, -THR), 0.0f);                     \
        cv = fmaf(-rs[2], mc[1], acc[2][1]);                               \
        rr = __builtin_amdgcn_rcpf(fmaf(sdu[2], seu[1], EPS19));           \
        O2.y = fmaxf(fmaf(fabsf(cv), rr, -THR), 0.0f);                     \
        cv = fmaf(-rs[2], mc[2], acc[2][2]);                               \
        rr = __builtin_amdgcn_rcpf(fmaf(sdu[2], seu[2], EPS19));           \
        O2.z = fmaxf(fmaf(fabsf(cv), rr, -THR), 0.0f);                     \
        cv = fmaf(-rs[2], mc[3], acc[2][3]);                               \
        rr = __builtin_amdgcn_rcpf(fmaf(sdu[2], seu[3], EPS19));           \
        O2.w = fmaxf(fmaf(fabsf(cv), rr, -THR), 0.0f);                     \
        cv = fmaf(-rs[3], mc[0], acc[3][0]);                               \
        rr = __builtin_amdgcn_rcpf(fmaf(sdu[3], seu[0], EPS19));           \
        O3.x = fmaxf(fmaf(fabsf(cv), rr, -THR), 0.0f);                     \
        cv = fmaf(-rs[3], mc[1], acc[3][1]);                               \
        rr = __builtin_amdgcn_rcpf(fmaf(sdu[3], seu[1], EPS19));           \
        O3.y = fmaxf(fmaf(fabsf(cv), rr, -THR), 0.0f);                     \
        cv = fmaf(-rs[3], mc[2], acc[3][2]);                               \
        rr = __builtin_amdgcn_rcpf(fmaf(sdu[3], seu[2], EPS19));           \
        O3.z = fmaxf(fmaf(fabsf(cv), rr, -THR), 0.0f);                     \
        cv = fmaf(-rs[3], mc[3], acc[3][3]);                               \
        rr = __builtin_amdgcn_rcpf(fmaf(sdu[3], seu[3], EPS19));           \
        O3.w = fmaxf(fmaf(fabsf(cv), rr, -THR), 0.0f);                     \
    }

    #define STORE4(S, O0, O1, O2, O3)                                      \
    {                                                                      \
        float* ob_ = obase + (size_t)(S) * (ND * ND);                      \
        *(f32x4*)&ob_[(r0     ) * ND + e0] = O0;                           \
        *(f32x4*)&ob_[(r0 +  4) * ND + e0] = O1;                           \
        *(f32x4*)&ob_[(r0 +  8) * ND + e0] = O2;                           \
        *(f32x4*)&ob_[(r0 + 12) * ND + e0] = O3;                           \
    }

    #define UPDATE(S)                                                      \
    {                                                                      \
        float an[4], ao[4];                                                \
        an[0] = win[(S) + NW][r0];                                         \
        an[1] = win[(S) + NW][r0 + 4];                                     \
        an[2] = win[(S) + NW][r0 + 8];                                     \
        an[3] = win[(S) + NW][r0 + 12];                                    \
        ao[0] = win[(S)][r0];                                              \
        ao[1] = win[(S)][r0 + 4];                                          \
        ao[2] = win[(S)][r0 + 8];                                          \
        ao[3] = win[(S)][r0 + 12];                                         \
        f32x4 nb  = *(const f32x4*)&win[(S) + NW][e0];                     \
        f32x4 obv = *(const f32x4*)&win[(S)][e0];                          \
        float bn[4] = {nb.x, nb.y, nb.z, nb.w};                            \
        float bo[4] = {obv.x, obv.y, obv.z, obv.w};                        \
        _Pragma("unroll")                                                  \
        for (int i = 0; i < 4; ++i) {                                      \
            rs[i] += an[i] - ao[i];                                        \
            rq[i]  = fmaf(an[i], an[i], fmaf(-ao[i], ao[i], rq[i]));       \
            _Pragma("unroll")                                              \
            for (int j = 0; j < 4; ++j)                                    \
                acc[i][j] = fmaf(an[i], bn[j], fmaf(-ao[i], bo[j], acc[i][j])); \
        }                                                                  \
        _Pragma("unroll")                                                  \
        for (int j = 0; j < 4; ++j) {                                      \
            cs[j] += bn[j] - bo[j];                                        \
            cq[j]  = fmaf(bn[j], bn[j], fmaf(-bo[j], bo[j], cq[j]));       \
        }                                                                  \
    }

    f32x4 oA0, oA1, oA2, oA3;
    f32x4 oB0, oB1, oB2, oB3;

    EPI(0, oA0, oA1, oA2, oA3);
    UPDATE(0);
    STORE4(0, oA0, oA1, oA2, oA3);

    #pragma unroll 1
    for (int k = 0; k < 7; ++k) {
        int s1 = 2 * k + 1;
        int s2 = 2 * k + 2;
        EPI(s1, oB0, oB1, oB2, oB3);
        UPDATE(s1);
        STORE4(s1, oB0, oB1, oB2, oB3);
        EPI(s2, oA0, oA1, oA2, oA3);
        UPDATE(s2);
        STORE4(s2, oA0, oA1, oA2, oA3);
    }

    EPI(15, oB0, oB1, oB2, oB3);
    STORE4(15, oB0, oB1, oB2, oB3);

    #undef EPI
    #undef STORE4
    #undef UPDATE
}

extern "C" void kernel_launch(void* const* d_in, const int* in_sizes, int n_in,
                              void* d_out, int out_size, void* d_ws, size_t ws_size,
                              hipStream_t stream) {
    const float* x = (const float*)d_in[0];
    float* out = (float*)d_out;
    dim3 grid(NB * (NL / CH));
    dim3 block(256);
    hipLaunchKernelGGL(dyn_corr_kernel, grid, block, 0, stream, x, out);
}